// Round 5
// baseline (3458.977 us; speedup 1.0000x reference)
//
#include <hip/hip_runtime.h>
#include <stdint.h>
#include <stddef.h>

// ---------------------------------------------------------------------------
// TextRNN: embed -> BiLSTM(512 steps) -> linear -> softmax   (MI355X gfx950)
//
// K0: transpose/cast Wx,Wh (f32 [256][1024]) -> bf16 [1024][256]  (col-major)
// K1: zx[dir][t][col][b] (bf16) = (emb[tokens] @ Wx + b) via mfma 16x16x32 bf16
// K2: 512-step recurrence, R5: XCD-local fast path with UNCONDITIONAL liveness.
//     - XCC_ID via __builtin_amdgcn_s_getreg (numeric encoding, compile-safe).
//     - 256 wgs; per-XCD roster claims 2 groups of 16 co-XCD wgs -> dir0/dir1.
//     - h exchange: tagged u32 words ((t+1)<<16 | bf16). Producers DUAL-store
//       sc0 (local L2, fast) + sc1 (L3 coherence point, safe). Consumers poll
//       sc0; sticky per-wave fallback to sc1 after 64 misses -> never hangs,
//       and dur_us tells us which path ran (<=1ms fast, >=2ms fallback).
//     - No producer drain: tag protocol needs no release ordering; poll-wait
//       absorbs store latency in parallel with load RT.
// K3: logits = [h_f|h_b] @ W_out + b_out; softmax -> d_out (f32 64x10)
// ---------------------------------------------------------------------------

typedef __attribute__((ext_vector_type(8))) short   short8;
typedef __attribute__((ext_vector_type(4))) float   f32x4;
typedef __attribute__((ext_vector_type(4))) unsigned short ushort4v;
typedef __attribute__((ext_vector_type(4))) unsigned int   uint4v;

// ws byte offsets
#define ZX_OFF    ((size_t)0)                        // 2*512*1024*64 bf16 = 134217728 B
#define WXT_OFF   ((size_t)134217728)                // 2*1024*256 bf16    = 1048576 B
#define WHT_OFF   ((size_t)135266304)                // 2*1024*256 bf16    = 1048576 B
#define HBUF_OFF  ((size_t)136314880)                // 2 dir * 2 buf * 64*256 u32 = 262144 B
#define SYNC_OFF  ((size_t)136577024)                // roster/dirclaim/done2/dirpub
#define WS_NEED   ((size_t)136577536)

__device__ __forceinline__ unsigned short f2bf(float f) {
  unsigned int u = __builtin_bit_cast(unsigned int, f);
  u += 0x7fffu + ((u >> 16) & 1u);            // RNE
  return (unsigned short)(u >> 16);
}
__device__ __forceinline__ float bf2f(unsigned short b) {
  unsigned int u = ((unsigned int)b) << 16;
  return __builtin_bit_cast(float, u);
}
__device__ __forceinline__ float sigf(float x) { return 1.0f / (1.0f + __expf(-x)); }
__device__ __forceinline__ float tanhf_(float x) {
  float t = __expf(-2.0f * fabsf(x));
  float r = (1.0f - t) / (1.0f + t);          // no inf/NaN for any x
  return copysignf(r, x);
}
// HW_REG_XCC_ID = hwreg id 20; s_getreg imm = id | (offset<<6) | ((size-1)<<11)
__device__ __forceinline__ int get_xcc_id() {
  return (int)(__builtin_amdgcn_s_getreg(20 | (0 << 6) | (3 << 11)) & 7u);
}

// ---------------------------------------------------------------------------
// K0: W (f32 [256][1024]) -> Wt (bf16 [1024][256]).  z selects matrix.
__global__ __launch_bounds__(256) void k0_transpose(
    const float* __restrict__ wxf, const float* __restrict__ wxb,
    const float* __restrict__ whf, const float* __restrict__ whb,
    unsigned short* __restrict__ wxt, unsigned short* __restrict__ wht) {
  __shared__ float lds[32][33];
  int mat = blockIdx.z;
  const float* src = (mat == 0) ? wxf : (mat == 1) ? wxb : (mat == 2) ? whf : whb;
  unsigned short* dst = (mat == 0) ? wxt : (mat == 1) ? (wxt + 262144)
                      : (mat == 2) ? wht : (wht + 262144);
  int k0 = blockIdx.x * 32;
  int n0 = blockIdx.y * 32;
  int tx = threadIdx.x & 31, ty = threadIdx.x >> 5;   // ty 0..7
#pragma unroll
  for (int r = 0; r < 4; r++) {
    int k = ty + r * 8;
    lds[k][tx] = src[(size_t)(k0 + k) * 1024 + n0 + tx];
  }
  __syncthreads();
#pragma unroll
  for (int r = 0; r < 4; r++) {
    int n = ty + r * 8;
    dst[(size_t)(n0 + n) * 256 + k0 + tx] = f2bf(lds[tx][n]);
  }
}

// ---------------------------------------------------------------------------
// K1: zx[dir][t][col][b] = emb[tok[b][t_src]] @ Wx + bias   (bf16 out)
// grid (512 t, 16 coltiles, 2 dir), block 256 (4 waves). Tile: 64 b x 64 cols.
__global__ __launch_bounds__(256) void k1_zx(
    const int* __restrict__ tokens, const float* __restrict__ emb,
    const unsigned short* __restrict__ wxt,   // [2][1024][256] bf16
    const float* __restrict__ bf_, const float* __restrict__ bb_,
    unsigned short* __restrict__ zx) {        // [2][512][1024][64] bf16
  int t  = blockIdx.x;
  int ct = blockIdx.y;
  int d  = blockIdx.z;
  int tid = threadIdx.x;
  int w = tid >> 6, lane = tid & 63, q = lane >> 4, l16 = lane & 15;
  int t_src = d ? (511 - t) : t;
  int b_row = w * 16 + l16;
  int tok = tokens[b_row * 512 + t_src];
  const float* embrow = emb + (size_t)tok * 256;
  const unsigned short* wxd = wxt + (size_t)d * 262144;
  const float* bias = d ? bb_ : bf_;

  f32x4 acc[4];
#pragma unroll
  for (int cs = 0; cs < 4; cs++) acc[cs] = {0.f, 0.f, 0.f, 0.f};

#pragma unroll
  for (int kt = 0; kt < 8; kt++) {
    int kbase = kt * 32 + q * 8;
    f32x4 v0 = *(const f32x4*)(embrow + kbase);
    f32x4 v1 = *(const f32x4*)(embrow + kbase + 4);
    short8 afrag;
#pragma unroll
    for (int j = 0; j < 4; j++) {
      afrag[j]     = (short)f2bf(v0[j]);
      afrag[4 + j] = (short)f2bf(v1[j]);
    }
#pragma unroll
    for (int cs = 0; cs < 4; cs++) {
      int gcol = ct * 64 + cs * 16 + l16;
      short8 bfrag = *(const short8*)(wxd + (size_t)gcol * 256 + kbase);
      acc[cs] = __builtin_amdgcn_mfma_f32_16x16x32_bf16(afrag, bfrag, acc[cs], 0, 0, 0);
    }
  }
  // epilogue: +bias, cast bf16, store [t][col][b] (4 consecutive b per lane)
#pragma unroll
  for (int cs = 0; cs < 4; cs++) {
    int gcol = ct * 64 + cs * 16 + l16;
    float bv = bias[gcol];
    ushort4v st;
#pragma unroll
    for (int r = 0; r < 4; r++) st[r] = f2bf(acc[cs][r] + bv);
    size_t idx = ((size_t)(d * 512 + t) * 1024 + gcol) * 64 + (w * 16 + q * 4);
    *(ushort4v*)(zx + idx) = st;
  }
}

// ---------------------------------------------------------------------------
// K2: recurrence. 256 wgs launched; 32 claim work via per-XCD roster:
// sync[0..7]=per-XCD arrival count, sync[8]=dir claim, sync[9]=done2,
// sync[16..31]=publication per (xcd,group). Claimed wg: dir d, role s (owns
// h-dims s*16..+16 = 64 gate cols, gate-major -> all 4 gates of (b,j) in one
// lane, c-state in registers).
__global__ __launch_bounds__(256) void k2_rnn(
    const unsigned short* __restrict__ zx,    // [2][512][1024][64] bf16
    const unsigned short* __restrict__ wht,   // [2][1024][256] bf16
    unsigned int* __restrict__ hbufw,         // [2][2][64][256] u32 tagged
    int* __restrict__ sync) {
  __shared__ int s_dir, s_role;
  int tid = threadIdx.x;
  if (tid == 0) {
    int xcd = get_xcc_id();
    int dir = -1, role = -1;
    int slot = __hip_atomic_fetch_add(&sync[xcd], 1, __ATOMIC_RELAXED,
                                      __HIP_MEMORY_SCOPE_AGENT);
    if (slot < 32) {
      int group = slot >> 4;
      role = slot & 15;
      int pidx = 16 + xcd * 2 + group;
      if (role == 15) {
        int dc = __hip_atomic_fetch_add(&sync[8], 1, __ATOMIC_RELAXED,
                                        __HIP_MEMORY_SCOPE_AGENT);
        int pub = (dc < 2) ? (dc + 1) : 3;    // 1=dir0, 2=dir1, 3=exit
        __hip_atomic_store(&sync[pidx], pub, __ATOMIC_RELEASE,
                           __HIP_MEMORY_SCOPE_AGENT);
        if (dc == 1)
          __hip_atomic_store(&sync[9], 1, __ATOMIC_RELEASE,
                             __HIP_MEMORY_SCOPE_AGENT);
        dir = (dc < 2) ? dc : -1;
      } else {
        while (true) {
          int v = __hip_atomic_load(&sync[pidx], __ATOMIC_ACQUIRE,
                                    __HIP_MEMORY_SCOPE_AGENT);
          if (v) { dir = (v <= 2) ? (v - 1) : -1; break; }
          if (__hip_atomic_load(&sync[9], __ATOMIC_ACQUIRE,
                                __HIP_MEMORY_SCOPE_AGENT)) {
            // publisher stores pidx before done2 (release order) -> recheck
            v = __hip_atomic_load(&sync[pidx], __ATOMIC_ACQUIRE,
                                  __HIP_MEMORY_SCOPE_AGENT);
            dir = (v && v <= 2) ? (v - 1) : -1;
            break;
          }
          __builtin_amdgcn_s_sleep(8);
        }
      }
    }
    s_dir = dir; s_role = role;
  }
  __syncthreads();
  int d = s_dir;
  int s = s_role;
  if (d < 0) return;                          // unclaimed wg exits

  int hdbase = s * 16;
  int w = tid >> 6, lane = tid & 63, q = lane >> 4, l16 = lane & 15;

  __shared__ unsigned short whtl[64][264];    // 33 KB, padded stride
  const unsigned short* whd = wht + (size_t)d * 262144;
  for (int idx = tid; idx < 2048; idx += 256) {
    int c = idx >> 5, kc = idx & 31;
    int grow = (c >> 4) * 256 + hdbase + (c & 15);    // gate*256 + hd
    *(short8*)(&whtl[c][kc * 8]) = *(const short8*)(whd + (size_t)grow * 256 + kc * 8);
  }
  __syncthreads();

  float cst[4] = {0.f, 0.f, 0.f, 0.f};        // c-state for (b=w*16+q*4+r, j=l16)
  unsigned int* hb = hbufw + (size_t)d * 32768;           // words
  int rowoff = (w * 16 + l16) * 256 + q * 8;              // consumer base (words)
  int srow   = (w * 16 + q * 4) * 256 + hdbase + l16;     // producer base (words)
  bool slow = false;                          // sticky sc1 fallback per wave

  for (int t = 0; t < 512; t++) {
    // prefetch zx for this step (normal cached loads; overlap with the poll)
    ushort4v zv[4];
    size_t zbase = (size_t)(d * 512 + t) * 65536;
#pragma unroll
    for (int cs = 0; cs < 4; cs++) {
      int gcol = cs * 256 + hdbase + l16;
      zv[cs] = *(const ushort4v*)(zx + zbase + (size_t)gcol * 64 + (w * 16 + q * 4));
    }

    // poll-load this lane's h A-fragments (tagged words) until tags >= t.
    const unsigned int* hp = hb + (t & 1) * 16384 + rowoff;
    unsigned int tlo = (unsigned int)t;
    uint4v hA[8], hB[8];
    int tries = 0;
    while (true) {
      if (!slow) {
        asm volatile(
            "global_load_dwordx4 %[a0], %[p], off sc0\n\t"
            "global_load_dwordx4 %[b0], %[p], off offset:16 sc0\n\t"
            "global_load_dwordx4 %[a1], %[p], off offset:128 sc0\n\t"
            "global_load_dwordx4 %[b1], %[p], off offset:144 sc0\n\t"
            "global_load_dwordx4 %[a2], %[p], off offset:256 sc0\n\t"
            "global_load_dwordx4 %[b2], %[p], off offset:272 sc0\n\t"
            "global_load_dwordx4 %[a3], %[p], off offset:384 sc0\n\t"
            "global_load_dwordx4 %[b3], %[p], off offset:400 sc0\n\t"
            "global_load_dwordx4 %[a4], %[p], off offset:512 sc0\n\t"
            "global_load_dwordx4 %[b4], %[p], off offset:528 sc0\n\t"
            "global_load_dwordx4 %[a5], %[p], off offset:640 sc0\n\t"
            "global_load_dwordx4 %[b5], %[p], off offset:656 sc0\n\t"
            "global_load_dwordx4 %[a6], %[p], off offset:768 sc0\n\t"
            "global_load_dwordx4 %[b6], %[p], off offset:784 sc0\n\t"
            "global_load_dwordx4 %[a7], %[p], off offset:896 sc0\n\t"
            "global_load_dwordx4 %[b7], %[p], off offset:912 sc0\n\t"
            "s_waitcnt vmcnt(0)"
            : [a0] "=v"(hA[0]), [b0] "=v"(hB[0]), [a1] "=v"(hA[1]), [b1] "=v"(hB[1]),
              [a2] "=v"(hA[2]), [b2] "=v"(hB[2]), [a3] "=v"(hA[3]), [b3] "=v"(hB[3]),
              [a4] "=v"(hA[4]), [b4] "=v"(hB[4]), [a5] "=v"(hA[5]), [b5] "=v"(hB[5]),
              [a6] "=v"(hA[6]), [b6] "=v"(hB[6]), [a7] "=v"(hA[7]), [b7] "=v"(hB[7])
            : [p] "v"(hp)
            : "memory");
      } else {
        asm volatile(
            "global_load_dwordx4 %[a0], %[p], off sc1\n\t"
            "global_load_dwordx4 %[b0], %[p], off offset:16 sc1\n\t"
            "global_load_dwordx4 %[a1], %[p], off offset:128 sc1\n\t"
            "global_load_dwordx4 %[b1], %[p], off offset:144 sc1\n\t"
            "global_load_dwordx4 %[a2], %[p], off offset:256 sc1\n\t"
            "global_load_dwordx4 %[b2], %[p], off offset:272 sc1\n\t"
            "global_load_dwordx4 %[a3], %[p], off offset:384 sc1\n\t"
            "global_load_dwordx4 %[b3], %[p], off offset:400 sc1\n\t"
            "global_load_dwordx4 %[a4], %[p], off offset:512 sc1\n\t"
            "global_load_dwordx4 %[b4], %[p], off offset:528 sc1\n\t"
            "global_load_dwordx4 %[a5], %[p], off offset:640 sc1\n\t"
            "global_load_dwordx4 %[b5], %[p], off offset:656 sc1\n\t"
            "global_load_dwordx4 %[a6], %[p], off offset:768 sc1\n\t"
            "global_load_dwordx4 %[b6], %[p], off offset:784 sc1\n\t"
            "global_load_dwordx4 %[a7], %[p], off offset:896 sc1\n\t"
            "global_load_dwordx4 %[b7], %[p], off offset:912 sc1\n\t"
            "s_waitcnt vmcnt(0)"
            : [a0] "=v"(hA[0]), [b0] "=v"(hB[0]), [a1] "=v"(hA[1]), [b1] "=v"(hB[1]),
              [a2] "=v"(hA[2]), [b2] "=v"(hB[2]), [a3] "=v"(hA[3]), [b3] "=v"(hB[3]),
              [a4] "=v"(hA[4]), [b4] "=v"(hB[4]), [a5] "=v"(hA[5]), [b5] "=v"(hB[5]),
              [a6] "=v"(hA[6]), [b6] "=v"(hB[6]), [a7] "=v"(hA[7]), [b7] "=v"(hB[7])
            : [p] "v"(hp)
            : "memory");
      }
      // one tag per 16B chunk; min of high16 across this lane's 16 chunks
      unsigned int mn = hA[0][0];
#pragma unroll
      for (int i = 1; i < 8; i++) mn = (hA[i][0] < mn) ? hA[i][0] : mn;
#pragma unroll
      for (int i = 0; i < 8; i++) mn = (hB[i][0] < mn) ? hB[i][0] : mn;
      if (__all((mn >> 16) >= tlo)) break;
      if (++tries >= 64) slow = true;         // sticky: placement/coherence miss
    }

    f32x4 acc[4];
#pragma unroll
    for (int cs = 0; cs < 4; cs++)
#pragma unroll
      for (int r = 0; r < 4; r++) acc[cs][r] = bf2f(zv[cs][r]);

#pragma unroll
    for (int kt = 0; kt < 8; kt++) {
      // pack 8 tagged words -> 8 bf16 (v_perm_b32, low halves)
      uint4v pk;
      pk[0] = __builtin_amdgcn_perm(hA[kt][1], hA[kt][0], 0x05040100u);
      pk[1] = __builtin_amdgcn_perm(hA[kt][3], hA[kt][2], 0x05040100u);
      pk[2] = __builtin_amdgcn_perm(hB[kt][1], hB[kt][0], 0x05040100u);
      pk[3] = __builtin_amdgcn_perm(hB[kt][3], hB[kt][2], 0x05040100u);
      short8 afrag = __builtin_bit_cast(short8, pk);
      int kbase = kt * 32 + q * 8;
#pragma unroll
      for (int cs = 0; cs < 4; cs++) {
        short8 bfrag = *(const short8*)(&whtl[cs * 16 + l16][kbase]);
        acc[cs] = __builtin_amdgcn_mfma_f32_16x16x32_bf16(afrag, bfrag, acc[cs], 0, 0, 0);
      }
    }

    unsigned int* hwn = hb + ((t + 1) & 1) * 16384 + srow;
    unsigned int wtag = ((unsigned int)(t + 1)) << 16;
    unsigned int sw[4];
#pragma unroll
    for (int r = 0; r < 4; r++) {
      float iv = sigf(acc[0][r]);
      float fv = sigf(acc[1][r]);
      float gv = tanhf_(acc[2][r]);
      float ov = sigf(acc[3][r]);
      cst[r] = fv * cst[r] + iv * gv;
      float hv = ov * tanhf_(cst[r]);
      sw[r] = wtag | (unsigned int)f2bf(hv);
    }
    // dual-store tagged h (rows at word-stride 256 = 1024 B): sc0 feeds the
    // local-L2 fast path, sc1 commits at L3 for the fallback. Same values ->
    // any ordering is final-state correct. NO drain: the data is the flag;
    // consumers' poll-wait absorbs store latency in parallel.
    asm volatile(
        "global_store_dword %[p], %[v0], off sc0\n\t"
        "global_store_dword %[p], %[v1], off offset:1024 sc0\n\t"
        "global_store_dword %[p], %[v2], off offset:2048 sc0\n\t"
        "global_store_dword %[p], %[v3], off offset:3072 sc0\n\t"
        "global_store_dword %[p], %[v0], off sc1\n\t"
        "global_store_dword %[p], %[v1], off offset:1024 sc1\n\t"
        "global_store_dword %[p], %[v2], off offset:2048 sc1\n\t"
        "global_store_dword %[p], %[v3], off offset:3072 sc1"
        :: [p] "v"(hwn), [v0] "v"(sw[0]), [v1] "v"(sw[1]),
           [v2] "v"(sw[2]), [v3] "v"(sw[3])
        : "memory");
  }
}

// ---------------------------------------------------------------------------
// K3: logits + softmax. 64 blocks (one per batch) x 64 threads (one wave).
// Final h_512 sits in buf0 of each dir (tagged words; low16 = bf16 value).
// k2's dispatch-end release + sc1 copies make them visible here.
__global__ __launch_bounds__(64) void k3_out(
    const unsigned int* __restrict__ hbufw,
    const float* __restrict__ wout, const float* __restrict__ bout,
    float* __restrict__ out) {
  int b = blockIdx.x, tid = threadIdx.x;
  const unsigned int* hf  = hbufw;            // dir0 buf0
  const unsigned int* hbk = hbufw + 32768;    // dir1 buf0
  float p[10];
#pragma unroll
  for (int l = 0; l < 10; l++) p[l] = 0.f;
  for (int k = tid; k < 512; k += 64) {
    unsigned int wd = (k < 256) ? hf[b * 256 + k] : hbk[b * 256 + k - 256];
    float f = bf2f((unsigned short)(wd & 0xffffu));
    const float* wr = wout + k * 10;
#pragma unroll
    for (int l = 0; l < 10; l++) p[l] += f * wr[l];
  }
#pragma unroll
  for (int off = 32; off; off >>= 1)
#pragma unroll
    for (int l = 0; l < 10; l++) p[l] += __shfl_down(p[l], off);
  if (tid == 0) {
    float lg[10], m = -1e30f;
#pragma unroll
    for (int l = 0; l < 10; l++) { lg[l] = p[l] + bout[l]; m = fmaxf(m, lg[l]); }
    float sum = 0.f;
#pragma unroll
    for (int l = 0; l < 10; l++) { lg[l] = __expf(lg[l] - m); sum += lg[l]; }
    float inv = 1.0f / sum;
#pragma unroll
    for (int l = 0; l < 10; l++) out[b * 10 + l] = lg[l] * inv;
  }
}

// ---------------------------------------------------------------------------
extern "C" void kernel_launch(void* const* d_in, const int* in_sizes, int n_in,
                              void* d_out, int out_size, void* d_ws, size_t ws_size,
                              hipStream_t stream) {
  const int*   tokens = (const int*)d_in[0];
  const float* emb    = (const float*)d_in[1];
  const float* wxf    = (const float*)d_in[2];
  const float* whf    = (const float*)d_in[3];
  const float* bf_    = (const float*)d_in[4];
  const float* wxb    = (const float*)d_in[5];
  const float* whb    = (const float*)d_in[6];
  const float* bb_    = (const float*)d_in[7];
  const float* wout   = (const float*)d_in[8];
  const float* bout   = (const float*)d_in[9];
  float* out = (float*)d_out;

  char* ws = (char*)d_ws;
  unsigned short* zx    = (unsigned short*)(ws + ZX_OFF);
  unsigned short* wxt   = (unsigned short*)(ws + WXT_OFF);
  unsigned short* wht   = (unsigned short*)(ws + WHT_OFF);
  unsigned int*   hbufw = (unsigned int*)(ws + HBUF_OFF);
  int*            sync  = (int*)(ws + SYNC_OFF);
  (void)ws_size; (void)in_sizes; (void)n_in; (void)out_size;   // needs WS_NEED bytes

  // zero h0 (tag 0 == step 0) + roster/claim words; 0xAAAA never matches a tag
  hipMemsetAsync(ws + HBUF_OFF, 0, 262144 + 512, stream);

  k0_transpose<<<dim3(8, 32, 4), 256, 0, stream>>>(wxf, wxb, whf, whb, wxt, wht);
  k1_zx<<<dim3(512, 16, 2), 256, 0, stream>>>(tokens, emb, wxt, bf_, bb_, zx);
  k2_rnn<<<256, 256, 0, stream>>>(zx, wht, hbufw, sync);
  k3_out<<<64, 64, 0, stream>>>(hbufw, wout, bout, out);
}

// Round 8
// 2762.251 us; speedup vs baseline: 1.2522x; 1.2522x over previous
//
#include <hip/hip_runtime.h>
#include <stdint.h>
#include <stddef.h>

// ---------------------------------------------------------------------------
// TextRNN: embed -> BiLSTM(512 steps) -> linear -> softmax   (MI355X gfx950)
//
// K0: transpose/cast Wx,Wh (f32 [256][1024]) -> bf16 [1024][256]  (col-major)
// K1: one wg computes BOTH dirs for a time-slot (same emb gather); 256-col
//     tiles; emb rows staged in LDS bf16. Gather redundancy 32x -> 4x.
// K2: R3-proven protocol (pure sc1 tagged words ((t<<16)|bf16), poll-the-data,
//     16 wgs/dir, gate-major cols, c-state in regs) with two R8 deltas:
//     (a) EARLY-CLOBBER (=&v) on all async-load asm outputs. R7 hung because
//         a plain =v output could alias a later load's address reg inside the
//         same asm block (async result landing before the last load issues).
//     (b) no producer drain: stores left in flight; the next step's single
//         burst (16 h polls + 4 zx) + vmcnt(0) retires them IN PARALLEL with
//         the poll RT. R3's serial drain-RT + poll-RT becomes one RT.
//     R4/R5 lesson: sc0/XCD-local exchange serves stale lines - don't.
// K3: logits = [h_f|h_b] @ W_out + b_out; softmax -> d_out (f32 64x10)
// ---------------------------------------------------------------------------

typedef __attribute__((ext_vector_type(8))) short   short8;
typedef __attribute__((ext_vector_type(4))) float   f32x4;
typedef __attribute__((ext_vector_type(4))) unsigned short ushort4v;
typedef __attribute__((ext_vector_type(4))) unsigned int   uint4v;
typedef __attribute__((ext_vector_type(2))) unsigned int   uint2v;

// ws byte offsets
#define ZX_OFF    ((size_t)0)                        // 2*512*1024*64 bf16 = 134217728 B
#define WXT_OFF   ((size_t)134217728)                // 2*1024*256 bf16    = 1048576 B
#define WHT_OFF   ((size_t)135266304)                // 2*1024*256 bf16    = 1048576 B
#define HBUF_OFF  ((size_t)136314880)                // 2 dir * 2 buf * 64*256 u32 = 262144 B
#define WS_NEED   ((size_t)136577024)

__device__ __forceinline__ unsigned short f2bf(float f) {
  unsigned int u = __builtin_bit_cast(unsigned int, f);
  u += 0x7fffu + ((u >> 16) & 1u);            // RNE
  return (unsigned short)(u >> 16);
}
__device__ __forceinline__ float bf2f(unsigned short b) {
  unsigned int u = ((unsigned int)b) << 16;
  return __builtin_bit_cast(float, u);
}
__device__ __forceinline__ float sigf(float x) { return 1.0f / (1.0f + __expf(-x)); }
__device__ __forceinline__ float tanhf_(float x) {
  float t = __expf(-2.0f * fabsf(x));
  float r = (1.0f - t) / (1.0f + t);          // no inf/NaN for any x
  return copysignf(r, x);
}

// ---------------------------------------------------------------------------
// K0: W (f32 [256][1024]) -> Wt (bf16 [1024][256]).  z selects matrix.
__global__ __launch_bounds__(256) void k0_transpose(
    const float* __restrict__ wxf, const float* __restrict__ wxb,
    const float* __restrict__ whf, const float* __restrict__ whb,
    unsigned short* __restrict__ wxt, unsigned short* __restrict__ wht) {
  __shared__ float lds[32][33];
  int mat = blockIdx.z;
  const float* src = (mat == 0) ? wxf : (mat == 1) ? wxb : (mat == 2) ? whf : whb;
  unsigned short* dst = (mat == 0) ? wxt : (mat == 1) ? (wxt + 262144)
                      : (mat == 2) ? wht : (wht + 262144);
  int k0 = blockIdx.x * 32;
  int n0 = blockIdx.y * 32;
  int tx = threadIdx.x & 31, ty = threadIdx.x >> 5;   // ty 0..7
#pragma unroll
  for (int r = 0; r < 4; r++) {
    int k = ty + r * 8;
    lds[k][tx] = src[(size_t)(k0 + k) * 1024 + n0 + tx];
  }
  __syncthreads();
#pragma unroll
  for (int r = 0; r < 4; r++) {
    int n = ty + r * 8;
    dst[(size_t)(n0 + n) * 256 + k0 + tx] = f2bf(lds[tx][n]);
  }
}

// ---------------------------------------------------------------------------
// K1: both dirs per wg. grid (512 ts, 4 ct), block 256 (4 waves).
// Tile: 64 batches x 256 cols x 2 dirs.  zx[d][t][col][b] bf16.
__global__ __launch_bounds__(256) void k1_zx(
    const int* __restrict__ tokens, const float* __restrict__ emb,
    const unsigned short* __restrict__ wxt,   // [2][1024][256] bf16
    const float* __restrict__ bf_, const float* __restrict__ bb_,
    unsigned short* __restrict__ zx) {        // [2][512][1024][64] bf16
  int ts = blockIdx.x;
  int ct = blockIdx.y;
  int tid = threadIdx.x;
  int w = tid >> 6, lane = tid & 63, q = lane >> 4, l16 = lane & 15;

  __shared__ unsigned short el[64][264];      // emb rows, bf16, padded
  {
    int row = tid >> 2, qq = tid & 3;         // 4 threads per row
    int tok = tokens[row * 512 + ts];
    const float* er = emb + (size_t)tok * 256 + qq * 64;
#pragma unroll
    for (int c = 0; c < 8; c++) {
      f32x4 v0 = *(const f32x4*)(er + c * 8);
      f32x4 v1 = *(const f32x4*)(er + c * 8 + 4);
      short8 pk;
#pragma unroll
      for (int j = 0; j < 4; j++) {
        pk[j]     = (short)f2bf(v0[j]);
        pk[4 + j] = (short)f2bf(v1[j]);
      }
      *(short8*)(&el[row][qq * 64 + c * 8]) = pk;
    }
  }
  __syncthreads();

  // A-fragments (shared by both dirs): batches [16w,16w+16)
  short8 afr[8];
#pragma unroll
  for (int kt = 0; kt < 8; kt++)
    afr[kt] = *(const short8*)(&el[16 * w + l16][kt * 32 + q * 8]);

#pragma unroll
  for (int d = 0; d < 2; d++) {
    const unsigned short* wxd = wxt + (size_t)d * 262144;
    const float* bias = d ? bb_ : bf_;
    f32x4 acc[16];
#pragma unroll
    for (int cs = 0; cs < 16; cs++) acc[cs] = {0.f, 0.f, 0.f, 0.f};
#pragma unroll
    for (int kt = 0; kt < 8; kt++) {
      int kbase = kt * 32 + q * 8;
#pragma unroll
      for (int cs = 0; cs < 16; cs++) {
        int col = ct * 256 + cs * 16 + l16;
        short8 bfrag = *(const short8*)(wxd + (size_t)col * 256 + kbase);
        acc[cs] = __builtin_amdgcn_mfma_f32_16x16x32_bf16(afr[kt], bfrag, acc[cs], 0, 0, 0);
      }
    }
    int tdst = d ? (511 - ts) : ts;
#pragma unroll
    for (int cs = 0; cs < 16; cs++) {
      int col = ct * 256 + cs * 16 + l16;
      float bv = bias[col];
      ushort4v st;
#pragma unroll
      for (int r = 0; r < 4; r++) st[r] = f2bf(acc[cs][r] + bv);
      size_t idx = ((size_t)(d * 512 + tdst) * 1024 + col) * 64 + (w * 16 + q * 4);
      *(ushort4v*)(zx + idx) = st;
    }
  }
}

// ---------------------------------------------------------------------------
// 16 sc1 dwordx4 loads of the h poll set (offsets kt*128 + {0,16})
#define POLL_LOADS_H                                             \
      "global_load_dwordx4 %[a0], %[p], off sc1\n\t"             \
      "global_load_dwordx4 %[b0], %[p], off offset:16 sc1\n\t"   \
      "global_load_dwordx4 %[a1], %[p], off offset:128 sc1\n\t"  \
      "global_load_dwordx4 %[b1], %[p], off offset:144 sc1\n\t"  \
      "global_load_dwordx4 %[a2], %[p], off offset:256 sc1\n\t"  \
      "global_load_dwordx4 %[b2], %[p], off offset:272 sc1\n\t"  \
      "global_load_dwordx4 %[a3], %[p], off offset:384 sc1\n\t"  \
      "global_load_dwordx4 %[b3], %[p], off offset:400 sc1\n\t"  \
      "global_load_dwordx4 %[a4], %[p], off offset:512 sc1\n\t"  \
      "global_load_dwordx4 %[b4], %[p], off offset:528 sc1\n\t"  \
      "global_load_dwordx4 %[a5], %[p], off offset:640 sc1\n\t"  \
      "global_load_dwordx4 %[b5], %[p], off offset:656 sc1\n\t"  \
      "global_load_dwordx4 %[a6], %[p], off offset:768 sc1\n\t"  \
      "global_load_dwordx4 %[b6], %[p], off offset:784 sc1\n\t"  \
      "global_load_dwordx4 %[a7], %[p], off offset:896 sc1\n\t"  \
      "global_load_dwordx4 %[b7], %[p], off offset:912 sc1"

// EARLY-CLOBBER (=&v): async load results must never alias address regs.
#define POLL_OUTS_H(A, B)                                                  \
      [a0] "=&v"(A[0]), [b0] "=&v"(B[0]), [a1] "=&v"(A[1]),                \
      [b1] "=&v"(B[1]), [a2] "=&v"(A[2]), [b2] "=&v"(B[2]),                \
      [a3] "=&v"(A[3]), [b3] "=&v"(B[3]), [a4] "=&v"(A[4]),                \
      [b4] "=&v"(B[4]), [a5] "=&v"(A[5]), [b5] "=&v"(B[5]),                \
      [a6] "=&v"(A[6]), [b6] "=&v"(B[6]), [a7] "=&v"(A[7]),                \
      [b7] "=&v"(B[7])

// K2: recurrence. 32 blocks (16/dir), 256 thr. Each wg owns 16 h-dims
// (cols gate-major: all 4 gates of (b,j) in one lane -> c-state in regs).
__global__ __launch_bounds__(256) void k2_rnn(
    const unsigned short* __restrict__ zx,    // [2][512][1024][64] bf16
    const unsigned short* __restrict__ wht,   // [2][1024][256] bf16
    unsigned int* __restrict__ hbufw) {       // [2][2][64][256] u32 tagged
  int d = blockIdx.x >> 4;
  int s = blockIdx.x & 15;
  int hdbase = s * 16;
  int tid = threadIdx.x;
  int w = tid >> 6, lane = tid & 63, q = lane >> 4, l16 = lane & 15;

  __shared__ unsigned short whtl[64][264];    // 33 KB, padded stride
  const unsigned short* whd = wht + (size_t)d * 262144;
  for (int idx = tid; idx < 2048; idx += 256) {
    int c = idx >> 5, kc = idx & 31;
    int grow = (c >> 4) * 256 + hdbase + (c & 15);    // gate*256 + hd
    *(short8*)(&whtl[c][kc * 8]) = *(const short8*)(whd + (size_t)grow * 256 + kc * 8);
  }
  __syncthreads();

  float cst[4] = {0.f, 0.f, 0.f, 0.f};        // c-state for (b=w*16+q*4+r, j=l16)
  unsigned int* hb = hbufw + (size_t)d * 32768;           // words
  int rowoff = (w * 16 + l16) * 256 + q * 8;              // consumer base (words)
  int srow   = (w * 16 + q * 4) * 256 + hdbase + l16;     // producer base (words)
  const unsigned short* zxd = zx + (size_t)d * 512 * 65536;

  uint4v hA[8], hB[8];
  uint2v zr[4];

  for (int t = 0; t < 512; t++) {
    const unsigned int* hp = hb + (t & 1) * 16384 + rowoff;
    unsigned int tg = (unsigned int)t << 16;
    const unsigned short* zb = zxd + (size_t)t * 65536 + (size_t)(hdbase + l16) * 64
                             + (w * 16 + q * 4);
    const unsigned short* zp0 = zb;
    const unsigned short* zp1 = zb + 256 * 64;
    const unsigned short* zp2 = zb + 512 * 64;
    const unsigned short* zp3 = zb + 768 * 64;

    // single burst: 16 h poll loads (sc1) + 4 zx loads (plain, cached).
    // The following vmcnt(0) retires last step's 4 h-stores IN PARALLEL with
    // this burst's RT (R3 paid a serial drain RT here).
    asm volatile(
        POLL_LOADS_H "\n\t"
        "global_load_dwordx2 %[z0], %[pz0], off\n\t"
        "global_load_dwordx2 %[z1], %[pz1], off\n\t"
        "global_load_dwordx2 %[z2], %[pz2], off\n\t"
        "global_load_dwordx2 %[z3], %[pz3], off"
        : POLL_OUTS_H(hA, hB),
          [z0] "=&v"(zr[0]), [z1] "=&v"(zr[1]), [z2] "=&v"(zr[2]), [z3] "=&v"(zr[3])
        : [p] "v"(hp), [pz0] "v"(zp0), [pz1] "v"(zp1), [pz2] "v"(zp2), [pz3] "v"(zp3)
        : "memory");

    while (true) {
      // tie all load dests so the tag check cannot move above the wait
      asm volatile("s_waitcnt vmcnt(0)"
                   : "+v"(hA[0]), "+v"(hA[1]), "+v"(hA[2]), "+v"(hA[3]),
                     "+v"(hA[4]), "+v"(hA[5]), "+v"(hA[6]), "+v"(hA[7]),
                     "+v"(hB[0]), "+v"(hB[1]), "+v"(hB[2]), "+v"(hB[3]),
                     "+v"(hB[4]), "+v"(hB[5]), "+v"(hB[6]), "+v"(hB[7]),
                     "+v"(zr[0]), "+v"(zr[1]), "+v"(zr[2]), "+v"(zr[3])
                   :: "memory");
      unsigned int bad =
          (hA[0][0] ^ tg) | (hB[0][0] ^ tg) | (hA[1][0] ^ tg) | (hB[1][0] ^ tg) |
          (hA[2][0] ^ tg) | (hB[2][0] ^ tg) | (hA[3][0] ^ tg) | (hB[3][0] ^ tg) |
          (hA[4][0] ^ tg) | (hB[4][0] ^ tg) | (hA[5][0] ^ tg) | (hB[5][0] ^ tg) |
          (hA[6][0] ^ tg) | (hB[6][0] ^ tg) | (hA[7][0] ^ tg) | (hB[7][0] ^ tg);
      if (__all((bad & 0xffff0000u) == 0)) break;
      // re-poll h only
      asm volatile(POLL_LOADS_H : POLL_OUTS_H(hA, hB) : [p] "v"(hp) : "memory");
    }

    f32x4 acc[4];
#pragma unroll
    for (int cs = 0; cs < 4; cs++) {
      ushort4v zv = __builtin_bit_cast(ushort4v, zr[cs]);
#pragma unroll
      for (int r = 0; r < 4; r++) acc[cs][r] = bf2f(zv[r]);
    }

#pragma unroll
    for (int kt = 0; kt < 8; kt++) {
      // pack 8 tagged words -> 8 bf16 (v_perm_b32, low halves)
      uint4v pk;
      pk[0] = __builtin_amdgcn_perm(hA[kt][1], hA[kt][0], 0x05040100u);
      pk[1] = __builtin_amdgcn_perm(hA[kt][3], hA[kt][2], 0x05040100u);
      pk[2] = __builtin_amdgcn_perm(hB[kt][1], hB[kt][0], 0x05040100u);
      pk[3] = __builtin_amdgcn_perm(hB[kt][3], hB[kt][2], 0x05040100u);
      short8 afrag = __builtin_bit_cast(short8, pk);
      int kbase = kt * 32 + q * 8;
#pragma unroll
      for (int cs = 0; cs < 4; cs++) {
        short8 bfrag = *(const short8*)(&whtl[cs * 16 + l16][kbase]);
        acc[cs] = __builtin_amdgcn_mfma_f32_16x16x32_bf16(afrag, bfrag, acc[cs], 0, 0, 0);
      }
    }

    unsigned int* hwn = hb + ((t + 1) & 1) * 16384 + srow;
    unsigned int wtag = ((unsigned int)(t + 1)) << 16;
    unsigned int sw[4];
#pragma unroll
    for (int r = 0; r < 4; r++) {
      float iv = sigf(acc[0][r]);
      float fv = sigf(acc[1][r]);
      float gv = tanhf_(acc[2][r]);
      float ov = sigf(acc[3][r]);
      cst[r] = fv * cst[r] + iv * gv;
      float hv = ov * tanhf_(cst[r]);
      sw[r] = wtag | (unsigned int)f2bf(hv);
    }
    // tagged h stores (rows at word-stride 256 = 1024 B), NO drain: next
    // step's vmcnt(0) (after its burst) retires them in parallel.
    asm volatile(
        "global_store_dword %[p], %[v0], off sc1\n\t"
        "global_store_dword %[p], %[v1], off offset:1024 sc1\n\t"
        "global_store_dword %[p], %[v2], off offset:2048 sc1\n\t"
        "global_store_dword %[p], %[v3], off offset:3072 sc1"
        :: [p] "v"(hwn), [v0] "v"(sw[0]), [v1] "v"(sw[1]),
           [v2] "v"(sw[2]), [v3] "v"(sw[3])
        : "memory");
  }
}

// ---------------------------------------------------------------------------
// K3: logits + softmax. 64 blocks (one per batch) x 64 threads (one wave).
// Final h_512 sits in buf0 of each dir (tagged words; low16 = bf16 value).
__global__ __launch_bounds__(64) void k3_out(
    const unsigned int* __restrict__ hbufw,
    const float* __restrict__ wout, const float* __restrict__ bout,
    float* __restrict__ out) {
  int b = blockIdx.x, tid = threadIdx.x;
  const unsigned int* hf  = hbufw;            // dir0 buf0
  const unsigned int* hbk = hbufw + 32768;    // dir1 buf0
  float p[10];
#pragma unroll
  for (int l = 0; l < 10; l++) p[l] = 0.f;
  for (int k = tid; k < 512; k += 64) {
    unsigned int wd = (k < 256) ? hf[b * 256 + k] : hbk[b * 256 + k - 256];
    float f = bf2f((unsigned short)(wd & 0xffffu));
    const float* wr = wout + k * 10;
#pragma unroll
    for (int l = 0; l < 10; l++) p[l] += f * wr[l];
  }
#pragma unroll
  for (int off = 32; off; off >>= 1)
#pragma unroll
    for (int l = 0; l < 10; l++) p[l] += __shfl_down(p[l], off);
  if (tid == 0) {
    float lg[10], m = -1e30f;
#pragma unroll
    for (int l = 0; l < 10; l++) { lg[l] = p[l] + bout[l]; m = fmaxf(m, lg[l]); }
    float sum = 0.f;
#pragma unroll
    for (int l = 0; l < 10; l++) { lg[l] = __expf(lg[l] - m); sum += lg[l]; }
    float inv = 1.0f / sum;
#pragma unroll
    for (int l = 0; l < 10; l++) out[b * 10 + l] = lg[l] * inv;
  }
}

// ---------------------------------------------------------------------------
extern "C" void kernel_launch(void* const* d_in, const int* in_sizes, int n_in,
                              void* d_out, int out_size, void* d_ws, size_t ws_size,
                              hipStream_t stream) {
  const int*   tokens = (const int*)d_in[0];
  const float* emb    = (const float*)d_in[1];
  const float* wxf    = (const float*)d_in[2];
  const float* whf    = (const float*)d_in[3];
  const float* bf_    = (const float*)d_in[4];
  const float* wxb    = (const float*)d_in[5];
  const float* whb    = (const float*)d_in[6];
  const float* bb_    = (const float*)d_in[7];
  const float* wout   = (const float*)d_in[8];
  const float* bout   = (const float*)d_in[9];
  float* out = (float*)d_out;

  char* ws = (char*)d_ws;
  unsigned short* zx    = (unsigned short*)(ws + ZX_OFF);
  unsigned short* wxt   = (unsigned short*)(ws + WXT_OFF);
  unsigned short* wht   = (unsigned short*)(ws + WHT_OFF);
  unsigned int*   hbufw = (unsigned int*)(ws + HBUF_OFF);
  (void)ws_size; (void)in_sizes; (void)n_in; (void)out_size;   // needs WS_NEED bytes

  // zero h0 (tag 0 == step 0); poison 0xAAAA never matches a tag (<= 512)
  hipMemsetAsync(ws + HBUF_OFF, 0, 262144, stream);

  k0_transpose<<<dim3(8, 32, 4), 256, 0, stream>>>(wxf, wxb, whf, whb, wxt, wht);
  k1_zx<<<dim3(512, 4), 256, 0, stream>>>(tokens, emb, wxt, bf_, bb_, zx);
  k2_rnn<<<32, 256, 0, stream>>>(zx, wht, hbufw);
  k3_out<<<64, 64, 0, stream>>>(hbufw, wout, bout, out);
}